// Round 9
// baseline (546.028 us; speedup 1.0000x reference)
//
#include <hip/hip_runtime.h>

#define TPB 256
#define BKT_SHIFT 8
#define BKT_SZ 256
#define CHUNK 8192
#define BKT_STRIDE 16384   // per-bucket region in part/csr; max bucket ~8.6K edges

// ------ phase 1: chunk histogram + run reservation + strided scatter ------
// Replaces count/scan1/scan2/part: one global atomicAdd per (block,bucket)
// reserves a contiguous run inside bucket d's region [d*BKT_STRIDE, ...).
__global__ void k_countpart(const int* __restrict__ src, const int* __restrict__ dst,
                            int* __restrict__ gcur, unsigned int* __restrict__ part,
                            int E, int NB) {
  __shared__ int hist[512];
  __shared__ int cur[512];
  int t = threadIdx.x;
  for (int d = t; d < NB; d += TPB) hist[d] = 0;
  __syncthreads();
  int base = blockIdx.x * CHUNK;
  int lim = min(base + CHUNK, E);
  for (int e = base + t; e < lim; e += TPB)
    atomicAdd(&hist[dst[e] >> BKT_SHIFT], 1);
  __syncthreads();
  for (int d = t; d < NB; d += TPB) {
    int h = hist[d];
    int b = h ? atomicAdd(&gcur[d], h) : 0;   // reserve run (global, 1 per block-bucket)
    cur[d] = d * BKT_STRIDE + b;
  }
  __syncthreads();
  for (int e = base + t; e < lim; e += TPB) {
    int dv = dst[e];
    int d = dv >> BKT_SHIFT;
    int p = atomicAdd(&cur[d], 1);
    part[p] = ((unsigned)src[e] << BKT_SHIFT) | (unsigned)(dv & (BKT_SZ - 1));
  }
}

// ------ phase 2: per-bucket CSR finalize: offs, deg, dis, csr (strided) ---
__global__ __launch_bounds__(256) void k_build(
    const unsigned int* __restrict__ part, const int* __restrict__ gcur,
    int* __restrict__ offs, int* __restrict__ degs, int* __restrict__ csr,
    float* __restrict__ dis, int n, int NB) {
  __shared__ int cnt[BKT_SZ];
  __shared__ int scn[BKT_SZ];
  int b = blockIdx.x, t = threadIdx.x;
  cnt[t] = 0;
  __syncthreads();
  int beg = b * BKT_STRIDE;
  int end = beg + gcur[b];
  for (int e = beg + t; e < end; e += 256)
    atomicAdd(&cnt[part[e] & (BKT_SZ - 1)], 1);
  __syncthreads();
  int deg = cnt[t];
  scn[t] = deg;
  __syncthreads();
  for (int d = 1; d < 256; d <<= 1) {
    int u = (t >= d) ? scn[t - d] : 0;
    __syncthreads();
    scn[t] += u;
    __syncthreads();
  }
  int excl = scn[t] - deg;
  int node = b * BKT_SZ + t;
  if (node < n) {
    offs[node] = beg + excl;
    degs[node] = deg;
    dis[node] = 1.0f / sqrtf((float)(deg + 1));   // +1 self loop
  }
  __syncthreads();
  cnt[t] = beg + excl;                            // reuse as cursor
  __syncthreads();
  for (int e = beg + t; e < end; e += 256) {
    unsigned int en = part[e];
    int p = atomicAdd(&cnt[en & (BKT_SZ - 1)], 1);
    csr[p] = (int)(en >> BKT_SHIFT);
  }
}

// ---------------- layer 1 GEMM: hs[i] = dis[i] * (x[i] @ W1) ---------
// wave-per-node; each lane owns W1 rows [lane*8, lane*8+8) in 128 VGPRs.
// Node-ahead prefetch of x to hide HBM latency.
__global__ __launch_bounds__(256) void k_gemm1(
    const float* __restrict__ x, const float* __restrict__ W1,
    const float* __restrict__ dis, float* __restrict__ hs, int n, int nwaves) {
  const int lane = threadIdx.x & 63;
  const int wave = blockIdx.x * 4 + (threadIdx.x >> 6);

  float w[8][16];
  #pragma unroll
  for (int m = 0; m < 8; ++m) {
    #pragma unroll
    for (int q = 0; q < 4; ++q) {
      float4 t = *reinterpret_cast<const float4*>(W1 + (lane * 8 + m) * 16 + q * 4);
      w[m][q * 4 + 0] = t.x; w[m][q * 4 + 1] = t.y;
      w[m][q * 4 + 2] = t.z; w[m][q * 4 + 3] = t.w;
    }
  }
  // exchange-halves reduction leaves lane l owning column brev4(l&15)
  const int c_out = ((lane & 1) << 3) | ((lane & 2) << 1) | ((lane & 4) >> 1) | ((lane & 8) >> 3);

  float4 a = {0, 0, 0, 0}, b = {0, 0, 0, 0};
  if (wave < n) {
    const float4* xp = reinterpret_cast<const float4*>(x + (size_t)wave * 512);
    a = xp[lane * 2]; b = xp[lane * 2 + 1];
  }

  for (int i = wave; i < n; ) {
    int inext = i + nwaves;
    float4 an = {0, 0, 0, 0}, bn = {0, 0, 0, 0};
    if (inext < n) {
      const float4* xp = reinterpret_cast<const float4*>(x + (size_t)inext * 512);
      an = xp[lane * 2]; bn = xp[lane * 2 + 1];
    }

    float xv[8] = {a.x, a.y, a.z, a.w, b.x, b.y, b.z, b.w};
    float acc[16];
    #pragma unroll
    for (int c = 0; c < 16; ++c) acc[c] = 0.f;
    #pragma unroll
    for (int m = 0; m < 8; ++m) {
      #pragma unroll
      for (int c = 0; c < 16; ++c) acc[c] = fmaf(xv[m], w[m][c], acc[c]);
    }

    {
      const bool hi = (lane & 1) != 0;
      #pragma unroll
      for (int v = 0; v < 8; ++v) {
        float send = hi ? acc[v] : acc[v + 8];
        float rcv = __shfl_xor(send, 1);
        acc[v] = (hi ? acc[v + 8] : acc[v]) + rcv;
      }
    }
    {
      const bool hi = (lane & 2) != 0;
      #pragma unroll
      for (int v = 0; v < 4; ++v) {
        float send = hi ? acc[v] : acc[v + 4];
        float rcv = __shfl_xor(send, 2);
        acc[v] = (hi ? acc[v + 4] : acc[v]) + rcv;
      }
    }
    {
      const bool hi = (lane & 4) != 0;
      #pragma unroll
      for (int v = 0; v < 2; ++v) {
        float send = hi ? acc[v] : acc[v + 2];
        float rcv = __shfl_xor(send, 4);
        acc[v] = (hi ? acc[v + 2] : acc[v]) + rcv;
      }
    }
    {
      const bool hi = (lane & 8) != 0;
      float send = hi ? acc[0] : acc[1];
      float rcv = __shfl_xor(send, 8);
      acc[0] = (hi ? acc[1] : acc[0]) + rcv;
    }
    float vsum = acc[0];
    vsum += __shfl_xor(vsum, 16);
    vsum += __shfl_xor(vsum, 32);

    if (lane < 16) hs[(size_t)i * 16 + c_out] = dis[i] * vsum;

    a = an; b = bn; i = inext;
  }
}

// ------- layer 1 aggregate + self-loop + ELU + layer-2 prescale ------
// wave-per-node, float4 gather: 4 lanes cover one edge's 64B row (one
// fully-used line), 16 edges in flight per wave.
__global__ __launch_bounds__(256) void k_agg1(
    const int* __restrict__ offs, const int* __restrict__ degs,
    const int* __restrict__ csr,
    const float* __restrict__ hs, const float* __restrict__ dis,
    const float* __restrict__ b1, float* __restrict__ h1s, int n) {
  int wave = blockIdx.x * 4 + (threadIdx.x >> 6);
  if (wave >= n) return;
  int lane = threadIdx.x & 63;
  int c4 = lane & 3, r = lane >> 2;
  int beg = offs[wave], end = beg + degs[wave];
  const float4* hs4 = reinterpret_cast<const float4*>(hs);

  float ax = 0.f, ay = 0.f, az = 0.f, aw = 0.f;
  int k = beg + r;
  int s = (k < end) ? csr[k] : 0;
  while (k < end) {
    int k2 = k + 16;
    int s2 = (k2 < end) ? csr[k2] : 0;
    float4 v = hs4[(size_t)s * 4 + c4];
    ax += v.x; ay += v.y; az += v.z; aw += v.w;
    s = s2; k = k2;
  }
  #pragma unroll
  for (int m = 4; m <= 32; m <<= 1) {
    ax += __shfl_xor(ax, m); ay += __shfl_xor(ay, m);
    az += __shfl_xor(az, m); aw += __shfl_xor(aw, m);
  }
  // self loop + scale + bias + elu
  float4 sf = hs4[(size_t)wave * 4 + c4];
  float di = dis[wave];
  float4 b1v = reinterpret_cast<const float4*>(b1)[c4];
  float ox = fmaf(di, ax + sf.x, b1v.x);
  float oy = fmaf(di, ay + sf.y, b1v.y);
  float oz = fmaf(di, az + sf.z, b1v.z);
  float ow = fmaf(di, aw + sf.w, b1v.w);
  float4 o;
  o.x = di * (ox > 0.f ? ox : expm1f(ox));
  o.y = di * (oy > 0.f ? oy : expm1f(oy));
  o.z = di * (oz > 0.f ? oz : expm1f(oz));
  o.w = di * (ow > 0.f ? ow : expm1f(ow));
  if (r == 0) reinterpret_cast<float4*>(h1s)[(size_t)wave * 4 + c4] = o;
}

// ------- layer 2 aggregate + 16x16 matvec + bias + log_softmax -------
__global__ __launch_bounds__(256) void k_agg2(
    const int* __restrict__ offs, const int* __restrict__ degs,
    const int* __restrict__ csr,
    const float* __restrict__ h1s, const float* __restrict__ dis,
    const float* __restrict__ W2, const float* __restrict__ b2,
    float* __restrict__ out, int n) {
  __shared__ float w2s[256];
  w2s[threadIdx.x] = W2[threadIdx.x];
  __syncthreads();
  int wave = blockIdx.x * 4 + (threadIdx.x >> 6);
  if (wave >= n) return;
  int lane = threadIdx.x & 63;
  int c4 = lane & 3, r = lane >> 2;
  int beg = offs[wave], end = beg + degs[wave];
  const float4* h4 = reinterpret_cast<const float4*>(h1s);

  float ax = 0.f, ay = 0.f, az = 0.f, aw = 0.f;
  int k = beg + r;
  int s = (k < end) ? csr[k] : 0;
  while (k < end) {
    int k2 = k + 16;
    int s2 = (k2 < end) ? csr[k2] : 0;
    float4 v = h4[(size_t)s * 4 + c4];
    ax += v.x; ay += v.y; az += v.z; aw += v.w;
    s = s2; k = k2;
  }
  #pragma unroll
  for (int m = 4; m <= 32; m <<= 1) {
    ax += __shfl_xor(ax, m); ay += __shfl_xor(ay, m);
    az += __shfl_xor(az, m); aw += __shfl_xor(aw, m);
  }
  // self loop + dst-side scale
  float4 sf = h4[(size_t)wave * 4 + c4];
  float di = dis[wave];
  float sx = di * (ax + sf.x);
  float sy = di * (ay + sf.y);
  float sz = di * (az + sf.z);
  float sw = di * (aw + sf.w);
  // redistribute: lane computes out column c = lane&15
  int c = lane & 15;
  int lbase = lane & ~3;
  float dot = 0.f;
  #pragma unroll
  for (int k16 = 0; k16 < 16; ++k16) {
    int srcl = lbase | (k16 >> 2);
    float comp = (k16 & 3) == 0 ? sx : (k16 & 3) == 1 ? sy : (k16 & 3) == 2 ? sz : sw;
    float vk = __shfl(comp, srcl);
    dot = fmaf(vk, w2s[k16 * 16 + c], dot);
  }
  float o = dot + b2[c];
  // log_softmax over the 16-lane class group
  float m = o;
  m = fmaxf(m, __shfl_xor(m, 1));
  m = fmaxf(m, __shfl_xor(m, 2));
  m = fmaxf(m, __shfl_xor(m, 4));
  m = fmaxf(m, __shfl_xor(m, 8));
  float ex = expf(o - m);
  float ssum = ex;
  ssum += __shfl_xor(ssum, 1);
  ssum += __shfl_xor(ssum, 2);
  ssum += __shfl_xor(ssum, 4);
  ssum += __shfl_xor(ssum, 8);
  if (lane < 16) out[(size_t)wave * 16 + c] = o - m - logf(ssum);
}

// ---------------- launch ----------------
extern "C" void kernel_launch(void* const* d_in, const int* in_sizes, int n_in,
                              void* d_out, int out_size, void* d_ws, size_t ws_size,
                              hipStream_t stream) {
  const float* x  = (const float*)d_in[0];
  const int*   ei = (const int*)d_in[1];
  const float* W1 = (const float*)d_in[2];
  const float* b1 = (const float*)d_in[3];
  const float* W2 = (const float*)d_in[4];
  const float* b2 = (const float*)d_in[5];
  float* out = (float*)d_out;

  const int n = in_sizes[0] / 512;
  const int E = in_sizes[1] / 2;
  const int* src = ei;
  const int* dst = ei + E;

  const int NB = (n + BKT_SZ - 1) >> BKT_SHIFT;       // 391 buckets
  const int NCHUNK = (E + CHUNK - 1) / CHUNK;         // 391 chunks

  char* ws = (char*)d_ws;
  size_t off = 0;
  auto alloc = [&](size_t bytes) -> void* {
    void* p = (void*)(ws + off);
    off += (bytes + 255) & ~(size_t)255;
    return p;
  };
  int*          gcur = (int*)alloc((size_t)NB * 4);
  unsigned int* part = (unsigned int*)alloc((size_t)NB * BKT_STRIDE * 4);
  int*          offs = (int*)alloc((size_t)n * 4);
  int*          degs = (int*)alloc((size_t)n * 4);
  int*          csr  = (int*)alloc((size_t)NB * BKT_STRIDE * 4);
  float*        dis  = (float*)alloc((size_t)n * 4);
  float*        hs   = (float*)alloc((size_t)n * 16 * 4);
  float*        h1s  = (float*)alloc((size_t)n * 16 * 4);
  (void)ws_size; (void)n_in; (void)out_size;

  const int ab = (n + 3) / 4;                         // 4 nodes per block

  hipMemsetAsync(gcur, 0, (size_t)NB * 4, stream);
  k_countpart<<<NCHUNK, TPB, 0, stream>>>(src, dst, gcur, part, E, NB);
  k_build    <<<NB, TPB, 0, stream>>>(part, gcur, offs, degs, csr, dis, n, NB);
  k_gemm1    <<<2048, TPB, 0, stream>>>(x, W1, dis, hs, n, 2048 * 4);
  k_agg1     <<<ab, TPB, 0, stream>>>(offs, degs, csr, hs, dis, b1, h1s, n);
  k_agg2     <<<ab, TPB, 0, stream>>>(offs, degs, csr, h1s, dis, W2, b2, out, n);
}